// Round 1
// baseline (192.034 us; speedup 1.0000x reference)
//
#include <hip/hip_runtime.h>
#include <math.h>

// B=65536, F=512, K=1299.
// einsum+gather == one dot/row vs labeled center.
// R1: same-address atomics serialize @13.3ns each (217us). R2: ws partials.
// R3: batched rows/wave (~50us kernel). R4/R5: nt loads neutral -> cache
// eviction theory refuted. Fixed harness reset ~145us (512MB poison + 131MB
// restore) dominates total; controllable = main(~43us) + reduce(~5us).
// R6: occupancy experiment - ROWS_PER_WAVE 8->4 halves data VGPRs
// (~5 waves/SIMD instead of ~3), 2x blocks. Discriminates latency-bound (a)
// vs external reset-writeback interference (b). Fusion via last-block
// counter rejected: 4096 atomics x 13ns = 54us tail > 5us dispatch saved.
// R7 (this round): infra failure on R6 bench -- resubmitted unchanged to get
// the discriminating measurement before any further structural change.

#define F_DIM 512
#define ROWS_PER_WAVE 4
#define WAVES_PER_BLOCK 4
#define NUM_BLOCKS 4096   // 4096 blk * 4 waves * 4 rows = 65536 rows exactly

typedef float fx4 __attribute__((ext_vector_type(4)));

__global__ __launch_bounds__(256) void prediction_loss_kernel(
    const float* __restrict__ input,    // (B, F)  -- streamed, zero reuse
    const float* __restrict__ factor,   // (B,)
    const int*   __restrict__ label,    // (B,)
    const float* __restrict__ centers,  // (K, F)  -- 2.66 MB, heavy reuse
    float* __restrict__ out,            // [0]=loss, [1..B]=predict_a
    float* __restrict__ partials)       // (NUM_BLOCKS,)
{
    const int wave = threadIdx.x >> 6;
    const int lane = threadIdx.x & 63;
    const int b0 = (blockIdx.x * WAVES_PER_BLOCK + wave) * ROWS_PER_WAVE;

    // --- label indices (scalarized) ---
    int c[ROWS_PER_WAVE];
    #pragma unroll
    for (int r = 0; r < ROWS_PER_WAVE; ++r)
        c[r] = __builtin_amdgcn_readfirstlane(label[b0 + r]);

    // --- 8 input loads, non-temporal (stream, no reuse) ---
    fx4 a0[ROWS_PER_WAVE], a1[ROWS_PER_WAVE];
    #pragma unroll
    for (int r = 0; r < ROWS_PER_WAVE; ++r) {
        const fx4* __restrict__ ip =
            (const fx4*)(input + (size_t)(b0 + r) * F_DIM);
        a0[r] = __builtin_nontemporal_load(ip + lane);
        a1[r] = __builtin_nontemporal_load(ip + lane + 64);
    }
    // --- 8 center loads, normal caching ---
    fx4 w0[ROWS_PER_WAVE], w1[ROWS_PER_WAVE];
    #pragma unroll
    for (int r = 0; r < ROWS_PER_WAVE; ++r) {
        const fx4* __restrict__ cp =
            (const fx4*)(centers + (size_t)c[r] * F_DIM);
        w0[r] = cp[lane];
        w1[r] = cp[lane + 64];
    }

    // --- 4 independent partial dots ---
    float dot[ROWS_PER_WAVE];
    #pragma unroll
    for (int r = 0; r < ROWS_PER_WAVE; ++r) {
        dot[r] = a0[r].x * w0[r].x + a0[r].y * w0[r].y
               + a0[r].z * w0[r].z + a0[r].w * w0[r].w
               + a1[r].x * w1[r].x + a1[r].y * w1[r].y
               + a1[r].z * w1[r].z + a1[r].w * w1[r].w;
    }

    // --- batched butterfly: 6 steps x 4 independent chains ---
    #pragma unroll
    for (int off = 32; off > 0; off >>= 1) {
        #pragma unroll
        for (int r = 0; r < ROWS_PER_WAVE; ++r)
            dot[r] += __shfl_xor(dot[r], off, 64);
    }
    // every lane holds all 4 complete dots.

    const int sel = lane & 3;
    float v = dot[0];
    #pragma unroll
    for (int r = 1; r < ROWS_PER_WAVE; ++r)
        v = (sel == r) ? dot[r] : v;

    const float pa = 12.0f * tanhf(v);

    float contrib = 0.0f;
    if (lane < ROWS_PER_WAVE) {
        out[1 + b0 + lane] = pa;
        const float d  = pa - factor[b0 + lane];
        const float ad = fabsf(d);
        contrib = (ad < 1.0f) ? 0.5f * d * d : (ad - 0.5f);
    }
    contrib += __shfl_xor(contrib, 2, 64);
    contrib += __shfl_xor(contrib, 1, 64);

    __shared__ float sh[WAVES_PER_BLOCK];
    if (lane == 0) sh[wave] = contrib;
    __syncthreads();
    if (threadIdx.x == 0)
        partials[blockIdx.x] =
            ((sh[0] + sh[1]) + (sh[2] + sh[3])) * (1.0f / 65536.0f);
}

__global__ __launch_bounds__(256) void reduce_partials_kernel(
    const float* __restrict__ partials, float* __restrict__ out)
{
    __shared__ float sh[4];
    const int wave = threadIdx.x >> 6;
    const int lane = threadIdx.x & 63;

    float s = 0.0f;
    #pragma unroll
    for (int i = 0; i < NUM_BLOCKS / 256; ++i)
        s += partials[threadIdx.x + i * 256];

    #pragma unroll
    for (int off = 32; off > 0; off >>= 1)
        s += __shfl_xor(s, off, 64);

    if (lane == 0) sh[wave] = s;
    __syncthreads();
    if (threadIdx.x == 0)
        out[0] = (sh[0] + sh[1]) + (sh[2] + sh[3]);
}

extern "C" void kernel_launch(void* const* d_in, const int* in_sizes, int n_in,
                              void* d_out, int out_size, void* d_ws, size_t ws_size,
                              hipStream_t stream) {
    const float* input   = (const float*)d_in[0];
    const float* factor  = (const float*)d_in[1];
    const int*   label   = (const int*)d_in[2];
    const float* centers = (const float*)d_in[3];
    float* out      = (float*)d_out;
    float* partials = (float*)d_ws;   // NUM_BLOCKS floats, fully overwritten

    prediction_loss_kernel<<<NUM_BLOCKS, 256, 0, stream>>>(
        input, factor, label, centers, out, partials);
    reduce_partials_kernel<<<1, 256, 0, stream>>>(partials, out);
}